// Round 10
// baseline (78.003 us; speedup 1.0000x reference)
//
#include <hip/hip_runtime.h>
#include <math.h>

#define BB 4
#define TT 1024
#define EE 512
#define HH 8
#define DD 64
#define BT (BB * TT)   // 4096

typedef _Float16 f16;
typedef __attribute__((ext_vector_type(8))) _Float16 f16x8;
typedef __attribute__((ext_vector_type(4))) float f32x4;

// ---------------------------------------------------------------------------
// Prep: y=0..3 weight planes (transposed f16), y=4/5 split q/kv into hi+lo
// f16 planes [BT][512]. Grid (1024, 6).
// ---------------------------------------------------------------------------
__global__ __launch_bounds__(256) void prep_k(
    const float* __restrict__ q, const float* __restrict__ kv,
    const float* __restrict__ Wq, const float* __restrict__ Wk,
    const float* __restrict__ Wv, const float* __restrict__ Wo,
    f16* __restrict__ wqh, f16* __restrict__ wql,
    f16* __restrict__ wkh, f16* __restrict__ wkl,
    f16* __restrict__ wvh, f16* __restrict__ woh,
    f16* __restrict__ qAhi, f16* __restrict__ qAlo,
    f16* __restrict__ kvAhi, f16* __restrict__ kvAlo) {
    const int t = threadIdx.x;
    const int y = blockIdx.y;
    if (y < 4) {
        int idx = blockIdx.x * 256 + t;        // 512*512 elems
        int k = idx & (EE - 1);
        int n = idx >> 9;
        if (y == 0) {
            float v = Wq[k * EE + n] * 512.0f; // fold dk*D scale (exact pow2)
            f16 hi = (f16)v;
            wqh[n * EE + k] = hi;
            wql[n * EE + k] = (f16)(v - (float)hi);
        } else if (y == 1) {
            int d = n >> 3, h = n & 7;
            int sn = (((DD - d) & (DD - 1)) << 3) | h;  // K'[.,d]=K[.,(D-d)%D]
            float v = Wk[k * EE + sn];
            f16 hi = (f16)v;
            wkh[n * EE + k] = hi;
            wkl[n * EE + k] = (f16)(v - (float)hi);
        } else if (y == 2) {
            wvh[n * EE + k] = (f16)Wv[k * EE + n];
        } else {
            woh[n * EE + k] = (f16)Wo[k * EE + n];
        }
    } else {
        const float* src = (y == 4) ? q : kv;
        f16* dh = (y == 4) ? qAhi : kvAhi;
        f16* dl = (y == 4) ? qAlo : kvAlo;
        int base = (blockIdx.x * 256 + t) * 8;
        float4 a = *(const float4*)&src[base];
        float4 c = *(const float4*)&src[base + 4];
        float xs[8] = {a.x, a.y, a.z, a.w, c.x, c.y, c.z, c.w};
        f16x8 hi, lo;
#pragma unroll
        for (int e = 0; e < 8; ++e) {
            f16 hh = (f16)xs[e];
            hi[e] = hh;
            lo[e] = (f16)(xs[e] - (float)hh);
        }
        *(f16x8*)&dh[base] = hi;
        *(f16x8*)&dl[base] = lo;
    }
}

// ---------------------------------------------------------------------------
// Fused projection. Grid (BT/128, EE/64, 2), block 256 (4 waves).
// z=0: Q from (qAhi,qAlo); z=1: K' and V from (kvAhi,kvAlo).
// Tile 128x64, BK=32, dbuf LDS + 2-DEEP reg prefetch (two named reg sets,
// 2-unrolled ks loop; loads get ~2 iterations to land).
// V stored fragment-packed: vP[h][tile64][kf][dvt][lane][8].
// ---------------------------------------------------------------------------
__global__ __launch_bounds__(256) void proj_k(
    const f16* __restrict__ qAhi, const f16* __restrict__ qAlo,
    const f16* __restrict__ kvAhi, const f16* __restrict__ kvAlo,
    const f16* __restrict__ wqh, const f16* __restrict__ wql,
    const f16* __restrict__ wkh, const f16* __restrict__ wkl,
    const f16* __restrict__ wvh,
    f16* __restrict__ qhi, f16* __restrict__ qlo,
    f16* __restrict__ khi, f16* __restrict__ klo, f16* __restrict__ vP) {
    __shared__ __align__(16) f16 Ah_s[2][128][40];
    __shared__ __align__(16) f16 Al_s[2][128][40];
    __shared__ __align__(16) f16 Wh_s[2][64][40];
    __shared__ __align__(16) f16 Wl_s[2][64][40];
    __shared__ __align__(16) f16 Wv_s[2][64][40];
    f16 (*Ep)[136] = reinterpret_cast<f16(*)[136]>(&Ah_s[0][0][0]);

    const int t = threadIdx.x;
    const int w = t >> 6, l = t & 63;
    const int wm = w >> 1, wn = w & 1;
    const int fr = l & 15, fc = l >> 4;
    const int m0b = blockIdx.x * 128;
    const int n0b = blockIdx.y * 64;
    const int z   = blockIdx.z;
    const int ar = t >> 1, ak = t & 1;
    const int wr = t >> 2, wc = t & 3;

    const f16* AH = z ? kvAhi : qAhi;
    const f16* AL = z ? kvAlo : qAlo;
    const f16* WH = z ? wkh : wqh;
    const f16* WL = z ? wkl : wql;

    f32x4 accK[4][2], accV[4][2];
#pragma unroll
    for (int i = 0; i < 4; ++i)
#pragma unroll
        for (int j = 0; j < 2; ++j) {
            accK[i][j] = f32x4{0.f, 0.f, 0.f, 0.f};
            accV[i][j] = f32x4{0.f, 0.f, 0.f, 0.f};
        }

    // two named prefetch register sets
    f16x8 ahA[2], alA[2], whA, wlA, wvA;
    f16x8 ahB[2], alB[2], whB, wlB, wvB;

    auto loadSet = [&](int k0, f16x8 (&ah)[2], f16x8 (&al)[2],
                       f16x8& wh, f16x8& wl, f16x8& wv) {
        size_t aoff = (size_t)(m0b + ar) * EE + k0 + ak * 16;
        ah[0] = *(const f16x8*)&AH[aoff];
        ah[1] = *(const f16x8*)&AH[aoff + 8];
        al[0] = *(const f16x8*)&AL[aoff];
        al[1] = *(const f16x8*)&AL[aoff + 8];
        size_t woff = (size_t)(n0b + wr) * EE + k0 + wc * 8;
        wh = *(const f16x8*)&WH[woff];
        wl = *(const f16x8*)&WL[woff];
        if (z) wv = *(const f16x8*)&wvh[woff];
    };
    auto stageSet = [&](int bf, f16x8 (&ah)[2], f16x8 (&al)[2],
                        f16x8& wh, f16x8& wl, f16x8& wv) {
        *(f16x8*)&Ah_s[bf][ar][ak * 16]     = ah[0];
        *(f16x8*)&Ah_s[bf][ar][ak * 16 + 8] = ah[1];
        *(f16x8*)&Al_s[bf][ar][ak * 16]     = al[0];
        *(f16x8*)&Al_s[bf][ar][ak * 16 + 8] = al[1];
        *(f16x8*)&Wh_s[bf][wr][wc * 8] = wh;
        *(f16x8*)&Wl_s[bf][wr][wc * 8] = wl;
        if (z) *(f16x8*)&Wv_s[bf][wr][wc * 8] = wv;
    };
    auto comp = [&](int bf) {
        f16x8 Ahf[4], Alf[4], Bh[2], Bl[2], Bv[2];
#pragma unroll
        for (int mi = 0; mi < 4; ++mi) {
            Ahf[mi] = *(const f16x8*)&Ah_s[bf][wm * 64 + mi * 16 + fr][fc * 8];
            Alf[mi] = *(const f16x8*)&Al_s[bf][wm * 64 + mi * 16 + fr][fc * 8];
        }
#pragma unroll
        for (int nj = 0; nj < 2; ++nj) {
            Bh[nj] = *(const f16x8*)&Wh_s[bf][wn * 32 + nj * 16 + fr][fc * 8];
            Bl[nj] = *(const f16x8*)&Wl_s[bf][wn * 32 + nj * 16 + fr][fc * 8];
            if (z) Bv[nj] = *(const f16x8*)&Wv_s[bf][wn * 32 + nj * 16 + fr][fc * 8];
        }
        __builtin_amdgcn_s_setprio(1);
#pragma unroll
        for (int mi = 0; mi < 4; ++mi)
#pragma unroll
            for (int nj = 0; nj < 2; ++nj) {
                accK[mi][nj] = __builtin_amdgcn_mfma_f32_16x16x32_f16(
                    Ahf[mi], Bh[nj], accK[mi][nj], 0, 0, 0);
                accK[mi][nj] = __builtin_amdgcn_mfma_f32_16x16x32_f16(
                    Ahf[mi], Bl[nj], accK[mi][nj], 0, 0, 0);
                accK[mi][nj] = __builtin_amdgcn_mfma_f32_16x16x32_f16(
                    Alf[mi], Bh[nj], accK[mi][nj], 0, 0, 0);
                if (z)
                    accV[mi][nj] = __builtin_amdgcn_mfma_f32_16x16x32_f16(
                        Ahf[mi], Bv[nj], accV[mi][nj], 0, 0, 0);
            }
        __builtin_amdgcn_s_setprio(0);
    };

    // prologue: K0 staged; K1 in set A; K2 in set B
    loadSet(0, ahA, alA, whA, wlA, wvA);
    stageSet(0, ahA, alA, whA, wlA, wvA);
    loadSet(32, ahA, alA, whA, wlA, wvA);
    loadSet(64, ahB, alB, whB, wlB, wvB);
    __syncthreads();

    for (int ks = 0; ks < 16; ks += 2) {
        comp(0);                                   // K(ks)
        stageSet(1, ahA, alA, whA, wlA, wvA);      // K(ks+1) -> buf1
        if (ks + 3 < 16) loadSet((ks + 3) * 32, ahA, alA, whA, wlA, wvA);
        __syncthreads();
        comp(1);                                   // K(ks+1)
        if (ks + 2 < 16) stageSet(0, ahB, alB, whB, wlB, wvB);  // K(ks+2)
        if (ks + 4 < 16) loadSet((ks + 4) * 32, ahB, alB, whB, wlB, wvB);
        __syncthreads();
    }

    // ---- epilogue (Ep aliases dead LDS) ----
    f16* dsthi = z ? khi : qhi;
    f16* dstlo = z ? klo : qlo;
#pragma unroll
    for (int mi = 0; mi < 4; ++mi)
#pragma unroll
        for (int nj = 0; nj < 2; ++nj)
#pragma unroll
            for (int r = 0; r < 4; ++r)
                Ep[wn * 32 + nj * 16 + fr][wm * 64 + mi * 16 + fc * 4 + r] =
                    (f16)accK[mi][nj][r];
    __syncthreads();
#pragma unroll
    for (int i = 0; i < 4; ++i) {
        int task = t * 4 + i;
        int mr = task >> 3, h = task & 7;
        f16x8 v;
#pragma unroll
        for (int d = 0; d < 8; ++d) v[d] = Ep[8 * d + h][mr];
        *(f16x8*)&dsthi[((size_t)h * BT + m0b + mr) * DD + (n0b >> 3)] = v;
    }
    __syncthreads();
#pragma unroll
    for (int mi = 0; mi < 4; ++mi)
#pragma unroll
        for (int nj = 0; nj < 2; ++nj)
#pragma unroll
            for (int r = 0; r < 4; ++r) {
                float x = accK[mi][nj][r];
                f16 hh = (f16)x;
                Ep[wn * 32 + nj * 16 + fr][wm * 64 + mi * 16 + fc * 4 + r] =
                    (f16)(x - (float)hh);
            }
    __syncthreads();
#pragma unroll
    for (int i = 0; i < 4; ++i) {
        int task = t * 4 + i;
        int mr = task >> 3, h = task & 7;
        f16x8 v;
#pragma unroll
        for (int d = 0; d < 8; ++d) v[d] = Ep[8 * d + h][mr];
        *(f16x8*)&dstlo[((size_t)h * BT + m0b + mr) * DD + (n0b >> 3)] = v;
    }
    if (z) {
        __syncthreads();
#pragma unroll
        for (int mi = 0; mi < 4; ++mi)
#pragma unroll
            for (int nj = 0; nj < 2; ++nj)
#pragma unroll
                for (int r = 0; r < 4; ++r)
                    Ep[wn * 32 + nj * 16 + fr][wm * 64 + mi * 16 + fc * 4 + r] =
                        (f16)accV[mi][nj][r];
        __syncthreads();
        // V fragment-packed store: vP[h][tile][kf][dvt][lane=lg*16+lq][e]
#pragma unroll
        for (int i = 0; i < 4; ++i) {
            int task = t * 4 + i;           // (nn 0..63, mg 0..15)
            int mg = task & 15, nn = task >> 4;
            int h = nn & 7, dl = nn >> 3;
            int d = (n0b >> 3) + dl;        // 0..63
            int koff = m0b + mg * 8;        // global key row (8-key run)
            int tile = koff >> 6;
            int kf   = (koff >> 5) & 1;
            int lg2  = (koff >> 3) & 3;
            int dvt  = d >> 4, lqd = d & 15;
            f16x8 v = *(const f16x8*)&Ep[nn][mg * 8];
            size_t off = (((((size_t)h * 64 + tile) * 2 + kf) * 4 + dvt) * 64 +
                          lg2 * 16 + lqd) * 8;
            *(f16x8*)&vP[off] = v;
        }
    }
}

// ---------------------------------------------------------------------------
// Output GEMM: out = ctx(f16) @ Wo (f16) -> fp32. Tile 64x64, BK=64.
// ---------------------------------------------------------------------------
__global__ __launch_bounds__(256) void outmm_k(const f16* __restrict__ Af,
                                               const f16* __restrict__ WThi,
                                               float* __restrict__ out) {
    __shared__ __align__(16) f16 Ah_s[2][64][72];
    __shared__ __align__(16) f16 Wh_s[2][64][72];

    const int t = threadIdx.x;
    const int w = t >> 6, l = t & 63;
    const int wm = w >> 1, wn = w & 1;
    const int fr = l & 15, fc = l >> 4;
    const int m0b = blockIdx.x * 64;
    const int n0b = blockIdx.y * 64;
    const int sr = t >> 2, sch = t & 3;

    f32x4 acc[2][2];
#pragma unroll
    for (int i = 0; i < 2; ++i)
#pragma unroll
        for (int j = 0; j < 2; ++j) acc[i][j] = f32x4{0.f, 0.f, 0.f, 0.f};

    f16x8 af[2], wf[2];
    auto loadAB = [&](int k0) {
#pragma unroll
        for (int i = 0; i < 2; ++i) {
            af[i] = *(const f16x8*)&Af[(size_t)(m0b + sr) * EE + k0 + sch * 16 + i * 8];
            wf[i] = *(const f16x8*)&WThi[(size_t)(n0b + sr) * EE + k0 + sch * 16 + i * 8];
        }
    };
    auto stage = [&](int bf) {
#pragma unroll
        for (int i = 0; i < 2; ++i) {
            *(f16x8*)&Ah_s[bf][sr][sch * 16 + i * 8] = af[i];
            *(f16x8*)&Wh_s[bf][sr][sch * 16 + i * 8] = wf[i];
        }
    };

    loadAB(0);
    stage(0);
    __syncthreads();
    int cur = 0;
    for (int ks = 0; ks < 8; ++ks) {
        if (ks < 7) loadAB((ks + 1) * 64);
        f16x8 Ahf[2][2], Bhf[2][2];
#pragma unroll
        for (int mi = 0; mi < 2; ++mi)
#pragma unroll
            for (int kb = 0; kb < 2; ++kb)
                Ahf[mi][kb] =
                    *(const f16x8*)&Ah_s[cur][wm * 32 + mi * 16 + fr][kb * 32 + fc * 8];
#pragma unroll
        for (int nj = 0; nj < 2; ++nj)
#pragma unroll
            for (int kb = 0; kb < 2; ++kb)
                Bhf[nj][kb] =
                    *(const f16x8*)&Wh_s[cur][wn * 32 + nj * 16 + fr][kb * 32 + fc * 8];
        __builtin_amdgcn_s_setprio(1);
#pragma unroll
        for (int mi = 0; mi < 2; ++mi)
#pragma unroll
            for (int nj = 0; nj < 2; ++nj)
#pragma unroll
                for (int kb = 0; kb < 2; ++kb)
                    acc[mi][nj] = __builtin_amdgcn_mfma_f32_16x16x32_f16(
                        Ahf[mi][kb], Bhf[nj][kb], acc[mi][nj], 0, 0, 0);
        __builtin_amdgcn_s_setprio(0);
        if (ks < 7) stage(cur ^ 1);
        __syncthreads();
        cur ^= 1;
    }

#pragma unroll
    for (int mi = 0; mi < 2; ++mi)
#pragma unroll
        for (int nj = 0; nj < 2; ++nj)
#pragma unroll
            for (int r = 0; r < 4; ++r)
                out[(size_t)(m0b + wm * 32 + mi * 16 + fc * 4 + r) * EE +
                    n0b + wn * 32 + nj * 16 + fr] = acc[mi][nj][r];
}

// ---------------------------------------------------------------------------
// MFMA flash attention, T15 pipeline: QK^T(t+1) issued BEFORE softmax(t) so
// the next tile's MFMA burst overlaps the current softmax VALU chain.
// K dbuf in LDS (loads 1 full iter ahead), V fragments double-buffered in
// regs (coalesced packed loads), defer-max, XCD-swizzled grid (512).
// ---------------------------------------------------------------------------
__global__ __launch_bounds__(256) void attn_mfma_k(const f16* __restrict__ qhiP,
    const f16* __restrict__ qloP, const f16* __restrict__ khiP,
    const f16* __restrict__ kloP, const f16* __restrict__ vP,
    f16* __restrict__ ctx) {
    __shared__ __align__(16) f16 Khi[2][64][64];   // XOR-swizzled 16B chunks
    __shared__ __align__(16) f16 Klo[2][64][64];
    __shared__ __align__(16) f16 Pl[4][16][88];    // per-wave P[q][key]

    const int bid = blockIdx.x;                 // 0..511
    const int swz = (bid & 7) * 64 + (bid >> 3);
    const int bx = swz & 15;
    const int h  = (swz >> 4) & 7;
    const int b  = swz >> 7;

    const int t  = threadIdx.x;
    const int w  = t >> 6;
    const int l  = t & 63;
    const int lg = l >> 4;
    const int lq = l & 15;
    const int q0 = bx * 64 + w * 16;
    const size_t plane = ((size_t)h * BT + (size_t)b * TT) * DD;

    f16x8 Qhi[2], Qlo[2];
#pragma unroll
    for (int kf = 0; kf < 2; ++kf) {
        size_t qo = plane + (size_t)(q0 + lq) * DD + kf * 32 + lg * 8;
        Qhi[kf] = *(const f16x8*)&qhiP[qo];
        Qlo[kf] = *(const f16x8*)&qloP[qo];
    }

    f32x4 Oacc[4];
#pragma unroll
    for (int i = 0; i < 4; ++i) Oacc[i] = f32x4{0.f, 0.f, 0.f, 0.f};
    float m = -1e30f, lsum = 0.f;

    const int sr = t >> 2, sch = t & 3;
    f16x8 kh[2], kl[2];

    auto loadK = [&](int kt0) {
        size_t off = plane + (size_t)(kt0 + sr) * DD + sch * 16;
        kh[0] = *(const f16x8*)&khiP[off];
        kh[1] = *(const f16x8*)&khiP[off + 8];
        kl[0] = *(const f16x8*)&kloP[off];
        kl[1] = *(const f16x8*)&kloP[off + 8];
    };
    auto stageK = [&](int bf) {
#pragma unroll
        for (int i = 0; i < 2; ++i) {
            int chunk = sch * 2 + i;
            int dsw = chunk ^ (sr & 7);
            *(f16x8*)&Khi[bf][sr][dsw * 8] = kh[i];
            *(f16x8*)&Klo[bf][sr][dsw * 8] = kl[i];
        }
    };

    f16x8 bvA[2][4], bvB[2][4];
    auto loadBV = [&](int kt0, f16x8 (&bv)[2][4]) {
        const f16* tb = vP + ((size_t)h * 64 + ((b * TT + kt0) >> 6)) * 4096;
#pragma unroll
        for (int kf = 0; kf < 2; ++kf)
#pragma unroll
            for (int dvt = 0; dvt < 4; ++dvt)
                bv[kf][dvt] = *(const f16x8*)&tb[((kf * 4 + dvt) * 64 + l) * 8];
    };

    f32x4 ScA[4], ScB[4];
    auto QK = [&](int curb, f32x4 (&Sc)[4]) {
        __builtin_amdgcn_s_setprio(1);
#pragma unroll
        for (int kt = 0; kt < 4; ++kt) {
            f32x4 c = f32x4{0.f, 0.f, 0.f, 0.f};
            int keyr = kt * 16 + lq;
#pragma unroll
            for (int kf = 0; kf < 2; ++kf) {
                int sw = (kf * 4 + lg) ^ (keyr & 7);
                f16x8 ahi = *(const f16x8*)&Khi[curb][keyr][sw * 8];
                f16x8 alo = *(const f16x8*)&Klo[curb][keyr][sw * 8];
                c = __builtin_amdgcn_mfma_f32_16x16x32_f16(ahi, Qhi[kf], c, 0, 0, 0);
                c = __builtin_amdgcn_mfma_f32_16x16x32_f16(ahi, Qlo[kf], c, 0, 0, 0);
                c = __builtin_amdgcn_mfma_f32_16x16x32_f16(alo, Qhi[kf], c, 0, 0, 0);
            }
            Sc[kt] = c;
        }
        __builtin_amdgcn_s_setprio(0);
    };

    auto SMPV = [&](const f32x4 (&Sc)[4], const f16x8 (&bv)[2][4]) {
        float sv[16];
#pragma unroll
        for (int kt = 0; kt < 4; ++kt)
#pragma unroll
            for (int r = 0; r < 4; ++r) sv[kt * 4 + r] = Sc[kt][r];
        float tm = sv[0];
#pragma unroll
        for (int i = 1; i < 16; ++i) tm = fmaxf(tm, sv[i]);
        tm = fmaxf(tm, __shfl_xor(tm, 16));
        tm = fmaxf(tm, __shfl_xor(tm, 32));

        bool skip = __all(tm <= m + 8.0f);
        float Mn = m, corr = 1.0f;
        if (!skip) {
            Mn = fmaxf(m, tm);
            corr = __expf(m - Mn);
        }
        float ps = 0.f;
        f16 ph[16];
#pragma unroll
        for (int i = 0; i < 16; ++i) {
            float p = __expf(sv[i] - Mn);
            ps += p;
            ph[i] = (f16)p;
        }
        ps += __shfl_xor(ps, 16);
        ps += __shfl_xor(ps, 32);
        if (skip) {
            lsum += ps;
        } else {
            lsum = lsum * corr + ps;
            m = Mn;
        }

#pragma unroll
        for (int kt = 0; kt < 4; ++kt)
#pragma unroll
            for (int rp = 0; rp < 4; rp += 2) {
                union { f16 h; unsigned short u; } u0, u1;
                u0.h = ph[kt * 4 + rp]; u1.h = ph[kt * 4 + rp + 1];
                unsigned int pk = ((unsigned int)u1.u << 16) | u0.u;
                *(unsigned int*)&Pl[w][lq][kt * 16 + lg * 4 + rp] = pk;
            }

        if (!skip) {
            float cq[4];
#pragma unroll
            for (int r = 0; r < 4; ++r) cq[r] = __shfl(corr, lg * 4 + r);
#pragma unroll
            for (int dvt = 0; dvt < 4; ++dvt)
#pragma unroll
                for (int r = 0; r < 4; ++r) Oacc[dvt][r] *= cq[r];
        }

        __builtin_amdgcn_s_setprio(1);
#pragma unroll
        for (int kf = 0; kf < 2; ++kf) {
            f16x8 pa = *(const f16x8*)&Pl[w][lq][kf * 32 + lg * 8];
#pragma unroll
            for (int dvt = 0; dvt < 4; ++dvt)
                Oacc[dvt] = __builtin_amdgcn_mfma_f32_16x16x32_f16(
                    pa, bv[kf][dvt], Oacc[dvt], 0, 0, 0);
        }
        __builtin_amdgcn_s_setprio(0);
    };

    // ---- prologue: buf0=K0, buf1=K1, bvA=V0, ScA=S(0) ----
    loadK(0);
    stageK(0);
    loadK(64);            // K1 -> regs
    loadBV(0, bvA);
    __syncthreads();      // buf0 visible (drains K1/bv0 loads once)
    QK(0, ScA);           // S(0)
    stageK(1);            // K1 -> buf1
    __syncthreads();      // buf1 visible

    for (int t2 = 0; t2 < 16; t2 += 2) {
        const int kt0 = t2 << 6;
        // ---- even tile t2 ----
        loadBV(kt0 + 64, bvB);               // V(t2+1)
        if (t2 + 2 < 16) loadK(kt0 + 128);   // K(t2+2) -> regs
        QK(1, ScB);                          // S(t2+1) from buf1 (MFMA)
        SMPV(ScA, bvA);                      // softmax+PV tile t2 (VALU overlaps)
        if (t2 + 2 < 16) stageK(0);          // K(t2+2) -> buf0
        __syncthreads();
        // ---- odd tile t2+1 ----
        if (t2 + 2 < 16) loadBV(kt0 + 128, bvA);   // V(t2+2)
        if (t2 + 3 < 16) loadK(kt0 + 192);         // K(t2+3) -> regs
        if (t2 + 2 < 16) QK(0, ScA);               // S(t2+2) from buf0
        SMPV(ScB, bvB);                            // tile t2+1
        if (t2 + 3 < 16) stageK(1);                // K(t2+3) -> buf1
        if (t2 + 2 < 16) __syncthreads();
    }

    float linv = 1.0f / lsum;
    float lq4[4];
#pragma unroll
    for (int r = 0; r < 4; ++r) lq4[r] = __shfl(linv, lg * 4 + r);
#pragma unroll
    for (int r = 0; r < 4; ++r) {
        f16* crow = ctx + (size_t)(b * TT + q0 + lg * 4 + r) * EE + h * DD;
#pragma unroll
        for (int dvt = 0; dvt < 4; ++dvt)
            crow[dvt * 16 + lq] = (f16)(Oacc[dvt][r] * lq4[r]);
    }
}

// ---------------------------------------------------------------------------
extern "C" void kernel_launch(void* const* d_in, const int* in_sizes, int n_in,
                              void* d_out, int out_size, void* d_ws, size_t ws_size,
                              hipStream_t stream) {
    const float* q  = (const float*)d_in[0];
    const float* kv = (const float*)d_in[1];
    const float* Wq = (const float*)d_in[2];
    const float* Wk = (const float*)d_in[3];
    const float* Wv = (const float*)d_in[4];
    const float* Wo = (const float*)d_in[5];
    float* out = (float*)d_out;

    f16* ws = (f16*)d_ws;
    const size_t PL  = (size_t)HH * BT * DD;   // 2,097,152 f16 per plane
    const size_t WPL = (size_t)EE * EE;
    f16* qhi   = ws + 0 * PL;
    f16* qlo   = ws + 1 * PL;
    f16* khi   = ws + 2 * PL;
    f16* klo   = ws + 3 * PL;
    f16* vPck  = ws + 4 * PL;      // packed V fragments [H][64][2][4][64][8]
    f16* ctx   = ws + 5 * PL;      // [BT][512]
    f16* qAhi  = ws + 6 * PL;
    f16* qAlo  = ws + 7 * PL;
    f16* kvAhi = ws + 8 * PL;
    f16* kvAlo = ws + 9 * PL;
    f16* wqh = ws + 10 * PL;
    f16* wql = wqh + 1 * WPL;
    f16* wkh = wqh + 2 * WPL;
    f16* wkl = wqh + 3 * WPL;
    f16* wvh = wqh + 4 * WPL;
    f16* woh = wqh + 5 * WPL;

    prep_k<<<dim3(1024, 6), dim3(256), 0, stream>>>(
        q, kv, Wq, Wk, Wv, Wo, wqh, wql, wkh, wkl, wvh, woh,
        qAhi, qAlo, kvAhi, kvAlo);

    proj_k<<<dim3(BT / 128, EE / 64, 2), dim3(256), 0, stream>>>(
        qAhi, qAlo, kvAhi, kvAlo, wqh, wql, wkh, wkl, wvh,
        qhi, qlo, khi, klo, vPck);

    attn_mfma_k<<<dim3(512), dim3(256), 0, stream>>>(
        qhi, qlo, khi, klo, vPck, ctx);

    outmm_k<<<dim3(BT / 64, EE / 64), dim3(256), 0, stream>>>(ctx, woh, out);
}